// Round 11
// baseline (65.513 us; speedup 1.0000x reference)
//
#include <hip/hip_runtime.h>

#define T_N 256
#define O_N 64
#define K_N 16
#define HW_N (224 * 224)      // 50176
#define DM 768
#define DO 2048
#define OMEGA_F 1e-6f

typedef float f32x4 __attribute__((ext_vector_type(4)));

// ---- proj decomposition: column-tiles x K-segments, atomic split-K ----
#define PCOLS 64
#define DSEG 64
#define NSEG (DM / DSEG)                 // 12
#define NT_O (DO / PCOLS)                // 32
#define NT_F (DM / PCOLS)                // 12
#define NB_PROJ ((NT_O + NT_F) * NSEG)   // 528
#define SUBB 4
#define NB_HIST (T_N * SUBB)             // 1024
#define NB_OBJ (T_N * O_N / 4)           // 4096

// ============ K1: proj blocks [0..527] (atomic split-K) + hist blocks [528..1551] (register bins)
__global__ __launch_bounds__(256) void fusedA(const float* __restrict__ me,
                                              const float* __restrict__ Wo, const float* __restrict__ bo,
                                              const float* __restrict__ Wf, const float* __restrict__ bf,
                                              const int* __restrict__ masks,
                                              float* __restrict__ proj_obj, float* __restrict__ proj_frame,
                                              float* __restrict__ counts_partial) {
    __shared__ float partial[4][K_N][PCOLS];   // 16 KB (proj)
    __shared__ float me_s[K_N * DSEG];         // 4 KB  (proj)
    __shared__ int hist_red[4][16];            // 256 B (hist)
    const int b = blockIdx.x;
    const int tid = threadIdx.x;

    if (b < NB_PROJ) {
        // ---- proj: one 64-col x 64-d partial tile, atomically accumulated (proven R4)
        const int tile = b / NSEG, seg = b - tile * NSEG;
        const float* W; const float* bias; float* out; int ld; int j0;
        if (tile < NT_O) { W = Wo; bias = bo; out = proj_obj;   ld = DO; j0 = tile * PCOLS; }
        else             { W = Wf; bias = bf; out = proj_frame; ld = DM; j0 = (tile - NT_O) * PCOLS; }
        const int d0 = seg * DSEG;

        for (int i = tid; i < K_N * DSEG; i += 256) {
            int k = i >> 6, dd = i & 63;
            me_s[i] = me[k * DM + d0 + dd];
        }
        __syncthreads();

        const int jj = tid & (PCOLS - 1);
        const int s  = tid >> 6;            // wave id 0..3
        const int j  = j0 + jj;
        const int db = s * 16;

        float acc[K_N];
        #pragma unroll
        for (int k = 0; k < K_N; ++k) acc[k] = 0.f;

        #pragma unroll
        for (int dd = 0; dd < 16; ++dd) {
            float w = W[(size_t)(d0 + db + dd) * ld + j];      // coalesced
            #pragma unroll
            for (int k = 0; k < K_N; ++k)
                acc[k] += me_s[k * DSEG + db + dd] * w;        // LDS broadcast
        }
        #pragma unroll
        for (int k = 0; k < K_N; ++k) partial[s][k][jj] = acc[k];
        __syncthreads();

        for (int o = tid; o < K_N * PCOLS; o += 256) {
            int k = o >> 6, c = o & 63;
            float v = partial[0][k][c] + partial[1][k][c]
                    + partial[2][k][c] + partial[3][k][c];
            if (seg == NSEG - 1) v += bias[j0 + c];
            atomicAdd(&out[k * ld + j0 + c], v);
        }
    } else {
        // ---- hist: 16 labels in 4 u32 of 4x8-bit register fields; zero LDS in pixel loop.
        const int hb = b - NB_PROJ;
        const int t = hb >> 2, sub = hb & 3;
        unsigned c0 = 0, c1 = 0, c2 = 0, c3 = 0;
        const int4* p = (const int4*)(masks + (size_t)t * HW_N);
        const int chunk = HW_N / 4 / SUBB;          // 3136
        const int end = (sub + 1) * chunk;
        for (int i = sub * chunk + tid; i < end; i += 256) {
            int4 v = p[i];
            #define ACC(val) { int u = (val) - 1; \
                unsigned inc = ((val) > 0) ? (1u << ((u & 3) << 3)) : 0u; \
                int q = u >> 2; \
                c0 += (q == 0) ? inc : 0u; c1 += (q == 1) ? inc : 0u; \
                c2 += (q == 2) ? inc : 0u; c3 += (q == 3) ? inc : 0u; }
            ACC(v.x) ACC(v.y) ACC(v.z) ACC(v.w)
            #undef ACC
        }
        unsigned r0 = c0 & 0x00FF00FFu, r1 = (c0 >> 8) & 0x00FF00FFu;
        unsigned r2 = c1 & 0x00FF00FFu, r3 = (c1 >> 8) & 0x00FF00FFu;
        unsigned r4 = c2 & 0x00FF00FFu, r5 = (c2 >> 8) & 0x00FF00FFu;
        unsigned r6 = c3 & 0x00FF00FFu, r7 = (c3 >> 8) & 0x00FF00FFu;
        #pragma unroll
        for (int m = 1; m < 64; m <<= 1) {
            r0 += __shfl_xor(r0, m, 64); r1 += __shfl_xor(r1, m, 64);
            r2 += __shfl_xor(r2, m, 64); r3 += __shfl_xor(r3, m, 64);
            r4 += __shfl_xor(r4, m, 64); r5 += __shfl_xor(r5, m, 64);
            r6 += __shfl_xor(r6, m, 64); r7 += __shfl_xor(r7, m, 64);
        }
        const int wave = tid >> 6, lane = tid & 63;
        if (lane == 0) {
            int* red = hist_red[wave];
            red[0]  = r0 & 0xFFFF; red[1]  = r1 & 0xFFFF; red[2]  = r0 >> 16; red[3]  = r1 >> 16;
            red[4]  = r2 & 0xFFFF; red[5]  = r3 & 0xFFFF; red[6]  = r2 >> 16; red[7]  = r3 >> 16;
            red[8]  = r4 & 0xFFFF; red[9]  = r5 & 0xFFFF; red[10] = r4 >> 16; red[11] = r5 >> 16;
            red[12] = r6 & 0xFFFF; red[13] = r7 & 0xFFFF; red[14] = r6 >> 16; red[15] = r7 >> 16;
        }
        __syncthreads();
        if (tid < K_N) {
            int s = hist_red[0][tid] + hist_red[1][tid]
                  + hist_red[2][tid] + hist_red[3][tid];
            counts_partial[((size_t)sub * T_N + t) * K_N + tid] = (float)s;
        }
    }
}

// ============ K2: obj blocks [0..4095] (wave-per-row, branchless, NT stores) + frame [4096..4351]
__global__ __launch_bounds__(256) void fusedB(const float* __restrict__ obj_feat,
                                              const int* __restrict__ obj_entity,
                                              const float* __restrict__ proj_obj,
                                              const float* __restrict__ frame_feat,
                                              const float* __restrict__ counts_partial,
                                              const float* __restrict__ proj_frame,
                                              const float* __restrict__ gamma,
                                              float* __restrict__ obj_out,
                                              float* __restrict__ frame_out) {
    __shared__ float c[K_N];
    const int b = blockIdx.x;
    const int tid = threadIdx.x;
    const float g = gamma[0];

    if (b < NB_OBJ) {
        // ---- obj: wave w owns one 2048-float row; branchless so the 8 obj_feat
        // loads issue WITHOUT waiting on the entity scalar load (no exec-mask dep).
        const int wave = tid >> 6;
        const int lane = tid & 63;
        const int row = b * 4 + wave;
        const int e = obj_entity[row];              // s_load, wave-uniform
        const f32x4* __restrict__ src = (const f32x4*)(obj_feat + (size_t)row * DO);
        f32x4* __restrict__ dst = (f32x4*)(obj_out + (size_t)row * DO);

        f32x4 a[8];
        #pragma unroll
        for (int it = 0; it < 8; ++it) a[it] = src[lane + it * 64];   // independent of e

        const float sc = (e > 0) ? g : 0.f;
        const int prow = (e > 0) ? (e - 1) : 0;
        const f32x4* __restrict__ pr = (const f32x4*)(proj_obj + (size_t)prow * DO);
        f32x4 p[8];
        #pragma unroll
        for (int it = 0; it < 8; ++it) p[it] = pr[lane + it * 64];    // L2-hot

        #pragma unroll
        for (int it = 0; it < 8; ++it) {
            f32x4 r = a[it] + sc * p[it];
            __builtin_nontemporal_store(r, &dst[lane + it * 64]);
        }
    } else {
        // ---- frame: one block per frame t
        const int t = b - NB_OBJ;
        if (tid < K_N) {
            float s = 0.f;
            #pragma unroll
            for (int sb = 0; sb < SUBB; ++sb)
                s += counts_partial[((size_t)sb * T_N + t) * K_N + tid];
            c[tid] = s;
        }
        __syncthreads();
        float tot = 0.f;
        #pragma unroll
        for (int k = 0; k < K_N; ++k) tot += c[k];
        const float inv = g / (OMEGA_F + tot);
        for (int j = tid; j < DM; j += 256) {
            float acc = 0.f;
            #pragma unroll
            for (int k = 0; k < K_N; ++k) acc += c[k] * proj_frame[k * DM + j];
            frame_out[t * DM + j] = frame_feat[t * DM + j] + acc * inv;
        }
    }
}

extern "C" void kernel_launch(void* const* d_in, const int* in_sizes, int n_in,
                              void* d_out, int out_size, void* d_ws, size_t ws_size,
                              hipStream_t stream) {
    const float* obj_feat   = (const float*)d_in[0];   // [T,O,DO]
    const float* frame_feat = (const float*)d_in[1];   // [T,DM]
    const float* me         = (const float*)d_in[2];   // [K,DM]
    const int*   obj_entity = (const int*)d_in[3];     // [T,O]
    const int*   masks      = (const int*)d_in[4];     // [T,H,W]
    const float* Wo         = (const float*)d_in[5];   // [DM,DO]
    const float* bo         = (const float*)d_in[6];   // [DO]
    const float* Wf         = (const float*)d_in[7];   // [DM,DM]
    const float* bf         = (const float*)d_in[8];   // [DM]
    const float* gamma      = (const float*)d_in[9];   // scalar

    float* obj_out   = (float*)d_out;                          // [T,O,DO]
    float* frame_out = (float*)d_out + (size_t)T_N * O_N * DO; // [T,DM]

    float* ws = (float*)d_ws;
    float* proj_obj       = ws;                  // 16*2048 = 32768 floats
    float* proj_frame     = ws + 32768;          // 16*768  = 12288 floats
    float* counts_partial = ws + 32768 + 12288;  // 4*256*16 = 16384 floats

    // zero the atomic split-K accumulators (capture-legal memset node)
    hipMemsetAsync(ws, 0, (size_t)(32768 + 12288) * sizeof(float), stream);

    // K1: proj (atomic split-K) overlapped with hist (register bins)
    fusedA<<<NB_PROJ + NB_HIST, 256, 0, stream>>>(
        me, Wo, bo, Wf, bf, masks, proj_obj, proj_frame, counts_partial);
    // K2: obj stream (dominant, branchless) with frame riding in the tail
    fusedB<<<NB_OBJ + T_N, 256, 0, stream>>>(
        obj_feat, obj_entity, proj_obj, frame_feat, counts_partial, proj_frame,
        gamma, obj_out, frame_out);
}

// Round 12
// 64.563 us; speedup vs baseline: 1.0147x; 1.0147x over previous
//
#include <hip/hip_runtime.h>

#define T_N 256
#define O_N 64
#define K_N 16
#define HW_N (224 * 224)      // 50176
#define DM 768
#define DO 2048
#define OMEGA_F 1e-6f

typedef float f32x4 __attribute__((ext_vector_type(4)));

// ---- proj decomposition: column-tiles x K-segments, atomic split-K ----
#define PCOLS 64
#define DSEG 64
#define NSEG (DM / DSEG)                 // 12
#define NT_O (DO / PCOLS)                // 32
#define NT_F (DM / PCOLS)                // 12
#define NB_PROJ ((NT_O + NT_F) * NSEG)   // 528
#define SUBB 4
#define NB_HIST (T_N * SUBB)             // 1024
#define NB_OBJ (T_N * O_N / 4)           // 4096

// ============ K1: proj blocks [0..527] (atomic split-K) + hist blocks [528..1551] (register bins)
__global__ __launch_bounds__(256) void fusedA(const float* __restrict__ me,
                                              const float* __restrict__ Wo, const float* __restrict__ bo,
                                              const float* __restrict__ Wf, const float* __restrict__ bf,
                                              const int* __restrict__ masks,
                                              float* __restrict__ proj_obj, float* __restrict__ proj_frame,
                                              float* __restrict__ counts_partial) {
    __shared__ float partial[4][K_N][PCOLS];   // 16 KB (proj)
    __shared__ float me_s[K_N * DSEG];         // 4 KB  (proj)
    __shared__ int hist_red[4][16];            // 256 B (hist)
    const int b = blockIdx.x;
    const int tid = threadIdx.x;

    if (b < NB_PROJ) {
        // ---- proj: one 64-col x 64-d partial tile, atomically accumulated (proven R4)
        const int tile = b / NSEG, seg = b - tile * NSEG;
        const float* W; const float* bias; float* out; int ld; int j0;
        if (tile < NT_O) { W = Wo; bias = bo; out = proj_obj;   ld = DO; j0 = tile * PCOLS; }
        else             { W = Wf; bias = bf; out = proj_frame; ld = DM; j0 = (tile - NT_O) * PCOLS; }
        const int d0 = seg * DSEG;

        for (int i = tid; i < K_N * DSEG; i += 256) {
            int k = i >> 6, dd = i & 63;
            me_s[i] = me[k * DM + d0 + dd];
        }
        __syncthreads();

        const int jj = tid & (PCOLS - 1);
        const int s  = tid >> 6;            // wave id 0..3
        const int j  = j0 + jj;
        const int db = s * 16;

        float acc[K_N];
        #pragma unroll
        for (int k = 0; k < K_N; ++k) acc[k] = 0.f;

        #pragma unroll
        for (int dd = 0; dd < 16; ++dd) {
            float w = W[(size_t)(d0 + db + dd) * ld + j];      // coalesced
            #pragma unroll
            for (int k = 0; k < K_N; ++k)
                acc[k] += me_s[k * DSEG + db + dd] * w;        // LDS broadcast
        }
        #pragma unroll
        for (int k = 0; k < K_N; ++k) partial[s][k][jj] = acc[k];
        __syncthreads();

        for (int o = tid; o < K_N * PCOLS; o += 256) {
            int k = o >> 6, c = o & 63;
            float v = partial[0][k][c] + partial[1][k][c]
                    + partial[2][k][c] + partial[3][k][c];
            if (seg == NSEG - 1) v += bias[j0 + c];
            atomicAdd(&out[k * ld + j0 + c], v);
        }
    } else {
        // ---- hist: 16 labels in 4 u32 of 4x8-bit register fields; zero LDS in pixel loop.
        const int hb = b - NB_PROJ;
        const int t = hb >> 2, sub = hb & 3;
        unsigned c0 = 0, c1 = 0, c2 = 0, c3 = 0;
        const int4* p = (const int4*)(masks + (size_t)t * HW_N);
        const int chunk = HW_N / 4 / SUBB;          // 3136
        const int end = (sub + 1) * chunk;
        for (int i = sub * chunk + tid; i < end; i += 256) {
            int4 v = p[i];
            #define ACC(val) { int u = (val) - 1; \
                unsigned inc = ((val) > 0) ? (1u << ((u & 3) << 3)) : 0u; \
                int q = u >> 2; \
                c0 += (q == 0) ? inc : 0u; c1 += (q == 1) ? inc : 0u; \
                c2 += (q == 2) ? inc : 0u; c3 += (q == 3) ? inc : 0u; }
            ACC(v.x) ACC(v.y) ACC(v.z) ACC(v.w)
            #undef ACC
        }
        unsigned r0 = c0 & 0x00FF00FFu, r1 = (c0 >> 8) & 0x00FF00FFu;
        unsigned r2 = c1 & 0x00FF00FFu, r3 = (c1 >> 8) & 0x00FF00FFu;
        unsigned r4 = c2 & 0x00FF00FFu, r5 = (c2 >> 8) & 0x00FF00FFu;
        unsigned r6 = c3 & 0x00FF00FFu, r7 = (c3 >> 8) & 0x00FF00FFu;
        #pragma unroll
        for (int m = 1; m < 64; m <<= 1) {
            r0 += __shfl_xor(r0, m, 64); r1 += __shfl_xor(r1, m, 64);
            r2 += __shfl_xor(r2, m, 64); r3 += __shfl_xor(r3, m, 64);
            r4 += __shfl_xor(r4, m, 64); r5 += __shfl_xor(r5, m, 64);
            r6 += __shfl_xor(r6, m, 64); r7 += __shfl_xor(r7, m, 64);
        }
        const int wave = tid >> 6, lane = tid & 63;
        if (lane == 0) {
            int* red = hist_red[wave];
            red[0]  = r0 & 0xFFFF; red[1]  = r1 & 0xFFFF; red[2]  = r0 >> 16; red[3]  = r1 >> 16;
            red[4]  = r2 & 0xFFFF; red[5]  = r3 & 0xFFFF; red[6]  = r2 >> 16; red[7]  = r3 >> 16;
            red[8]  = r4 & 0xFFFF; red[9]  = r5 & 0xFFFF; red[10] = r4 >> 16; red[11] = r5 >> 16;
            red[12] = r6 & 0xFFFF; red[13] = r7 & 0xFFFF; red[14] = r6 >> 16; red[15] = r7 >> 16;
        }
        __syncthreads();
        if (tid < K_N) {
            int s = hist_red[0][tid] + hist_red[1][tid]
                  + hist_red[2][tid] + hist_red[3][tid];
            counts_partial[((size_t)sub * T_N + t) * K_N + tid] = (float)s;
        }
    }
}

// ============ K2: frame blocks [0..255] first, then obj blocks [256..4351]
// obj body: all 16 loads forced in flight via sched_barrier before the store cluster.
__global__ __launch_bounds__(256) void fusedB(const float* __restrict__ obj_feat,
                                              const int* __restrict__ obj_entity,
                                              const float* __restrict__ proj_obj,
                                              const float* __restrict__ frame_feat,
                                              const float* __restrict__ counts_partial,
                                              const float* __restrict__ proj_frame,
                                              const float* __restrict__ gamma,
                                              float* __restrict__ obj_out,
                                              float* __restrict__ frame_out) {
    __shared__ float c[K_N];
    const int b = blockIdx.x;
    const int tid = threadIdx.x;
    const float g = gamma[0];

    if (b >= T_N) {
        // ---- obj: wave w owns one 2048-float row; 64 lanes x 8 float4
        const int wave = tid >> 6;
        const int lane = tid & 63;
        const int row = (b - T_N) * 4 + wave;
        const int e = obj_entity[row];              // wave-uniform
        const f32x4* __restrict__ src = (const f32x4*)(obj_feat + (size_t)row * DO);
        f32x4* __restrict__ dst = (f32x4*)(obj_out + (size_t)row * DO);

        f32x4 a[8];
        #pragma unroll
        for (int it = 0; it < 8; ++it) a[it] = src[lane + it * 64];   // independent of e

        const float sc = (e > 0) ? g : 0.f;
        const int prow = (e > 0) ? (e - 1) : 0;
        const f32x4* __restrict__ pr = (const f32x4*)(proj_obj + (size_t)prow * DO);
        f32x4 p[8];
        #pragma unroll
        for (int it = 0; it < 8; ++it) p[it] = pr[lane + it * 64];    // L2-hot

        // Forbid the compiler from sinking loads into the store loop: all 16
        // dwordx4 loads must be issued before the first store (MLP depth 16).
        __builtin_amdgcn_sched_barrier(0);

        #pragma unroll
        for (int it = 0; it < 8; ++it) {
            f32x4 r = a[it] + sc * p[it];
            __builtin_nontemporal_store(r, &dst[lane + it * 64]);
        }
    } else {
        // ---- frame: one block per frame t (front of grid, no tail behind obj)
        const int t = b;
        if (tid < K_N) {
            float s = 0.f;
            #pragma unroll
            for (int sb = 0; sb < SUBB; ++sb)
                s += counts_partial[((size_t)sb * T_N + t) * K_N + tid];
            c[tid] = s;
        }
        __syncthreads();
        float tot = 0.f;
        #pragma unroll
        for (int k = 0; k < K_N; ++k) tot += c[k];
        const float inv = g / (OMEGA_F + tot);
        for (int j = tid; j < DM; j += 256) {
            float acc = 0.f;
            #pragma unroll
            for (int k = 0; k < K_N; ++k) acc += c[k] * proj_frame[k * DM + j];
            frame_out[t * DM + j] = frame_feat[t * DM + j] + acc * inv;
        }
    }
}

extern "C" void kernel_launch(void* const* d_in, const int* in_sizes, int n_in,
                              void* d_out, int out_size, void* d_ws, size_t ws_size,
                              hipStream_t stream) {
    const float* obj_feat   = (const float*)d_in[0];   // [T,O,DO]
    const float* frame_feat = (const float*)d_in[1];   // [T,DM]
    const float* me         = (const float*)d_in[2];   // [K,DM]
    const int*   obj_entity = (const int*)d_in[3];     // [T,O]
    const int*   masks      = (const int*)d_in[4];     // [T,H,W]
    const float* Wo         = (const float*)d_in[5];   // [DM,DO]
    const float* bo         = (const float*)d_in[6];   // [DO]
    const float* Wf         = (const float*)d_in[7];   // [DM,DM]
    const float* bf         = (const float*)d_in[8];   // [DM]
    const float* gamma      = (const float*)d_in[9];   // scalar

    float* obj_out   = (float*)d_out;                          // [T,O,DO]
    float* frame_out = (float*)d_out + (size_t)T_N * O_N * DO; // [T,DM]

    float* ws = (float*)d_ws;
    float* proj_obj       = ws;                  // 16*2048 = 32768 floats
    float* proj_frame     = ws + 32768;          // 16*768  = 12288 floats
    float* counts_partial = ws + 32768 + 12288;  // 4*256*16 = 16384 floats

    // zero the atomic split-K accumulators (capture-legal memset node)
    hipMemsetAsync(ws, 0, (size_t)(32768 + 12288) * sizeof(float), stream);

    // K1: proj (atomic split-K) overlapped with hist (register bins)
    fusedA<<<NB_PROJ + NB_HIST, 256, 0, stream>>>(
        me, Wo, bo, Wf, bf, masks, proj_obj, proj_frame, counts_partial);
    // K2: frame (front) + obj stream (deep-MLP, NT stores)
    fusedB<<<T_N + NB_OBJ, 256, 0, stream>>>(
        obj_feat, obj_entity, proj_obj, frame_feat, counts_partial, proj_frame,
        gamma, obj_out, frame_out);
}